// Round 10
// baseline (416.149 us; speedup 1.0000x reference)
//
#include <hip/hip_runtime.h>

typedef __attribute__((ext_vector_type(8))) __bf16 bf16x8;
typedef __attribute__((ext_vector_type(4))) float f32x4;
typedef __attribute__((ext_vector_type(4))) unsigned int u32x4;
typedef __attribute__((ext_vector_type(4))) unsigned short u16x4;
typedef __attribute__((ext_vector_type(8))) unsigned short u16x8;

__device__ __forceinline__ unsigned short f2bf(float x) {
  unsigned u = __builtin_bit_cast(unsigned, x);
  u += 0x7fffu + ((u >> 16) & 1u);
  return (unsigned short)(u >> 16);
}
__device__ __forceinline__ float bf2f(unsigned short h) {
  unsigned u = ((unsigned)h) << 16;
  return __builtin_bit_cast(float, u);
}
__device__ __forceinline__ bf16x8 ld_frag(const unsigned short* p) {
  u32x4 u = *(const u32x4*)p;
  return __builtin_bit_cast(bf16x8, u);
}
__device__ __forceinline__ void gload_lds16(const unsigned short* g, unsigned short* l) {
  __builtin_amdgcn_global_load_lds(
      (const __attribute__((address_space(1))) void*)g,
      (__attribute__((address_space(3))) void*)l, 16, 0, 0);
}

// ---------------- f32 -> bf16 conversion (vectorized) ----------------
__global__ __launch_bounds__(256) void cvt_bf16(const float* __restrict__ in,
                                                unsigned short* __restrict__ out, int n4) {
  int i = blockIdx.x * 256 + threadIdx.x;
  if (i >= n4) return;
  f32x4 v = *((const f32x4*)in + i);
  u16x4 o;
  #pragma unroll
  for (int j = 0; j < 4; ++j) o[j] = f2bf(v[j]);
  *((u16x4*)out + i) = o;
}

// ------- GEMM r10: C[M,N] = A[M,K]*B[N,K]^T, triple-buffered counted-vmcnt -------
// BM=BN=256, BK=32; 512 thr = 8 waves (2M x 4N), per-wave 128x64 (acc[8][4]).
// LDS 96KB = 3 bufs x (A 256x32 + B 256x32), chunk-XOR swizzle c^((row>>1)&3).
// Per K-tile: ph0 {ds_read a0-3,b0-3 | stage A(t+2) | bar | lgkm0 | 16 MFMA | bar}
//             ph1 {ds_read a4-7      | stage B(t+2) | bar | lgkm0 | 16 MFMA |
//                  vmcnt(4) [t+1 landed, t+2's 4 stay in flight] | bar}
// Never vmcnt(0) in main loop (T4). XCD-aware swizzle (nwg%8==0). M/256==16.
template <int WRITE_BF16>
__global__ __launch_bounds__(512, 2) void gemm3b(const unsigned short* __restrict__ A,
                                                 const unsigned short* __restrict__ B,
                                                 void* __restrict__ Cv,
                                                 int M, int N, int K) {
  __shared__ __align__(16) unsigned short SM[49152];  // 96 KB
  const int nwg = gridDim.x;
  const int swz = (blockIdx.x & 7) * (nwg >> 3) + (blockIdx.x >> 3);
  const int bx = swz & 15, by = swz >> 4;
  const int row0 = bx * 256, col0 = by * 256;
  const int tid = threadIdx.x;
  const int wave = tid >> 6, lane = tid & 63;
  const int g = lane >> 4, r = lane & 15;
  const int wm = (wave >> 2) * 128, wn = (wave & 3) * 64;
  const int NT = K >> 5;

  const unsigned short* Agb = A + (size_t)row0 * K;
  const unsigned short* Bgb = B + (size_t)col0 * K;

  f32x4 acc[8][4] = {};

  // stage granule u (512 x 16B) of a 256x32 tile at K-offset kt*32
  auto SU = [&](const unsigned short* src, unsigned short* dst, int kt, int u) {
    const int pos = u * 512 + tid;
    const int rw = pos >> 2, cc = pos & 3;
    gload_lds16(src + (size_t)rw * K + kt * 32 + ((cc ^ ((rw >> 1) & 3)) * 8),
                dst + pos * 8);
  };
  auto LDF = [&](const unsigned short* base, int row) {
    return ld_frag(base + row * 32 + ((g ^ ((row >> 1) & 3)) * 8));
  };

  // prologue: tiles 0,1 -> bufs 0,1 (8 loads); wait tile0 (4 stay in flight)
  SU(Agb, SM,         0, 0); SU(Agb, SM,         0, 1);
  SU(Bgb, SM + 8192,  0, 0); SU(Bgb, SM + 8192,  0, 1);
  SU(Agb, SM + 16384, 1, 0); SU(Agb, SM + 16384, 1, 1);
  SU(Bgb, SM + 24576, 1, 0); SU(Bgb, SM + 24576, 1, 1);
  asm volatile("s_waitcnt vmcnt(4)" ::: "memory");
  __builtin_amdgcn_s_barrier();

  for (int t = 0; t < NT; ++t) {
    const int ct = t % 3, st = (t + 2) % 3;
    const unsigned short* Ab = SM + ct * 16384;
    const unsigned short* Bb = Ab + 8192;
    unsigned short* An = SM + st * 16384;
    unsigned short* Bn = An + 8192;
    const bool pf = (t + 2 < NT);

    bf16x8 a[4], b[4];

    // ---- ph0: mi 0-3 ----
    a[0] = LDF(Ab, wm + r);      a[1] = LDF(Ab, wm + 16 + r);
    a[2] = LDF(Ab, wm + 32 + r); a[3] = LDF(Ab, wm + 48 + r);
    b[0] = LDF(Bb, wn + r);      b[1] = LDF(Bb, wn + 16 + r);
    b[2] = LDF(Bb, wn + 32 + r); b[3] = LDF(Bb, wn + 48 + r);
    if (pf) { SU(Agb, An, t + 2, 0); SU(Agb, An, t + 2, 1); }
    __builtin_amdgcn_s_barrier();
    asm volatile("s_waitcnt lgkmcnt(0)" ::: "memory");
    __builtin_amdgcn_sched_barrier(0);
    __builtin_amdgcn_s_setprio(1);
    #pragma unroll
    for (int mi = 0; mi < 4; ++mi)
      #pragma unroll
      for (int ni = 0; ni < 4; ++ni)
        acc[mi][ni] = __builtin_amdgcn_mfma_f32_16x16x32_bf16(a[mi], b[ni], acc[mi][ni], 0, 0, 0);
    __builtin_amdgcn_s_setprio(0);
    __builtin_amdgcn_s_barrier();

    // ---- ph1: mi 4-7 (b frags held) ----
    a[0] = LDF(Ab, wm + 64 + r); a[1] = LDF(Ab, wm + 80 + r);
    a[2] = LDF(Ab, wm + 96 + r); a[3] = LDF(Ab, wm + 112 + r);
    if (pf) { SU(Bgb, Bn, t + 2, 0); SU(Bgb, Bn, t + 2, 1); }
    __builtin_amdgcn_s_barrier();
    asm volatile("s_waitcnt lgkmcnt(0)" ::: "memory");
    __builtin_amdgcn_sched_barrier(0);
    __builtin_amdgcn_s_setprio(1);
    #pragma unroll
    for (int mi = 0; mi < 4; ++mi)
      #pragma unroll
      for (int ni = 0; ni < 4; ++ni)
        acc[4 + mi][ni] = __builtin_amdgcn_mfma_f32_16x16x32_bf16(a[mi], b[ni], acc[4 + mi][ni], 0, 0, 0);
    __builtin_amdgcn_s_setprio(0);
    if (pf) asm volatile("s_waitcnt vmcnt(4)" ::: "memory");
    else    asm volatile("s_waitcnt vmcnt(0)" ::: "memory");
    __builtin_amdgcn_s_barrier();
  }

  // epilogue
  #pragma unroll
  for (int mi = 0; mi < 8; ++mi)
    #pragma unroll
    for (int ni = 0; ni < 4; ++ni)
      #pragma unroll
      for (int rr = 0; rr < 4; ++rr) {
        const size_t idx = (size_t)(row0 + wm + mi * 16 + g * 4 + rr) * (size_t)N
                         + (col0 + wn + ni * 16 + r);
        if (WRITE_BF16) ((unsigned short*)Cv)[idx] = f2bf(acc[mi][ni][rr]);
        else            ((float*)Cv)[idx] = acc[mi][ni][rr];
      }
}

// ---------------- RoPE in-place on Q+K, vectorized (4 d-elems/thread) ----------------
__global__ __launch_bounds__(256) void rope_qk(unsigned short* __restrict__ qkv,
                                               const float* __restrict__ cs,
                                               const float* __restrict__ sn) {
  const int t = blockIdx.x * 256 + threadIdx.x;  // B*S*40*12 = 1,966,080 exact
  const int d4 = t % 12;
  const int rest = t / 12;
  const int head = rest % 40;
  const int row = rest / 40;                     // b*2048+s
  const size_t base = (size_t)row * 4608 + head * 96 + d4 * 4;
  const u16x4 a = *(const u16x4*)&qkv[base];
  const u16x4 bq = *(const u16x4*)&qkv[base + 48];
  const int cb = row * 96 + d4 * 4;
  const f32x4 c1 = *(const f32x4*)&cs[cb];
  const f32x4 s1 = *(const f32x4*)&sn[cb];
  const f32x4 c2 = *(const f32x4*)&cs[cb + 48];
  const f32x4 s2 = *(const f32x4*)&sn[cb + 48];
  u16x4 o1, o2;
  #pragma unroll
  for (int j = 0; j < 4; ++j) {
    const float x1 = bf2f(a[j]), x2 = bf2f(bq[j]);
    o1[j] = f2bf(x1 * c1[j] - x2 * s1[j]);
    o2[j] = f2bf(x2 * c2[j] + x1 * s2[j]);
  }
  *(u16x4*)&qkv[base] = o1;
  *(u16x4*)&qkv[base + 48] = o2;
}

// ---------------- V transpose: qkv[b,s,3840+kvh*96+d] -> vt[b,kvh,d,s] ----------------
__global__ __launch_bounds__(256) void vtrans(const unsigned short* __restrict__ qkv,
                                              unsigned short* __restrict__ vt) {
  __shared__ __align__(16) unsigned short T[64 * 104];
  const int s0 = blockIdx.x * 64;
  const int kvh = blockIdx.y, b = blockIdx.z;
  const int tid = threadIdx.x;
  #pragma unroll
  for (int it = 0; it < 3; ++it) {
    const int c = it * 256 + tid;
    const int sr = c / 12, d0 = (c % 12) * 8;
    *(u32x4*)&T[sr * 104 + d0] =
        *(const u32x4*)&qkv[(size_t)(b * 2048 + s0 + sr) * 4608 + 3840 + kvh * 96 + d0];
  }
  __syncthreads();
  #pragma unroll
  for (int it = 0; it < 3; ++it) {
    const int c = it * 256 + tid;
    const int dr = c >> 3, k0 = (c & 7) * 8;
    u16x8 o;
    #pragma unroll
    for (int j = 0; j < 8; ++j) o[j] = T[(k0 + j) * 104 + dr];
    *(u16x8*)&vt[((size_t)(b * 8 + kvh) * 96 + dr) * 2048 + s0 + k0] = o;
  }
}

// ---------------- Flash attention, causal GQA, swapped QK^T (unchanged r9) ----------------
__global__ __launch_bounds__(512) void attn_fwd(const unsigned short* __restrict__ qkv,
                                                const unsigned short* __restrict__ vt,
                                                unsigned short* __restrict__ ctx) {
  __shared__ __align__(16) unsigned short SMEM[40960];  // 80 KB
  const int wg = blockIdx.x;             // 0..255
  const int xcd = wg & 7, j = wg >> 3;   // j 0..31
  const int c = xcd + ((j >> 4) << 3);   // (b,kvh) id, 0..15
  const int b = c >> 3, kvh = c & 7;
  const int rj = j & 15;
  const int h = kvh * 4 + (rj >> 2);
  const int pr = rj & 3;                 // fold pair: qt in {7-pr, pr}
  const int tid = threadIdx.x;
  const int wave = tid >> 6, lane = tid & 63;
  const int g = lane >> 4, r = lane & 15;
  const float kLS = 0.14724445f;         // (1/sqrt(96)) * log2(e)

  const unsigned short* kgbase = qkv + (size_t)(b * 2048) * 4608 + 3072 + kvh * 96;
  const unsigned short* vgbase = vt + (size_t)(b * 8 + kvh) * 96 * 2048;

  auto STAGE = [&](int t, int bi) {
    const int kv0 = t * 64;
    unsigned short* kd = SMEM + bi * 6144;
    unsigned short* vd = SMEM + 12288 + bi * 6144;
    #pragma unroll
    for (int i = 0; i < 3; ++i) {
      const int l = i * 512 + tid;
      if (l < 768) {  // K: [dk][row][c], src chunk c^((row>>1)&3)
        const int dk = l >> 8, rem = l & 255;
        const int row = rem >> 2, cc = rem & 3;
        const int csrc = cc ^ ((row >> 1) & 3);
        gload_lds16(kgbase + (size_t)(kv0 + row) * 4608 + dk * 32 + csrc * 8, kd + l * 8);
      } else {        // V: [row][c], src chunk c^(row&7)
        const int lv = l - 768;
        const int row = lv >> 3, cc = lv & 7;
        const int csrc = cc ^ (row & 7);
        gload_lds16(vgbase + (size_t)row * 2048 + kv0 + csrc * 8, vd + lv * 8);
      }
    }
  };

  #pragma unroll 1
  for (int sel = 0; sel < 2; ++sel) {
    const int qt = sel ? pr : 7 - pr;
    const int nt = qt * 4 + 4;
    const int q0 = qt * 256 + wave * 32;

    __syncthreads();   // protect LDS (prev epilogue reads) before re-staging

    bf16x8 qf[2][3];
    #pragma unroll
    for (int qb = 0; qb < 2; ++qb)
      #pragma unroll
      for (int dk = 0; dk < 3; ++dk)
        qf[qb][dk] = ld_frag(&qkv[(size_t)(b * 2048 + q0 + qb * 16 + r) * 4608 + h * 96 + dk * 32 + g * 8]);

    f32x4 o[6][2] = {};
    float m_[2] = {-1e30f, -1e30f};
    float l_[2] = {0.f, 0.f};

    STAGE(0, 0);
    __syncthreads();

    for (int t = 0; t < nt; ++t) {
      const int cur = t & 1;
      if (t + 1 < nt) STAGE(t + 1, cur ^ 1);
      const int kv0 = t * 64;
      const unsigned short* Ks = SMEM + cur * 6144;
      const unsigned short* Vs = SMEM + 12288 + cur * 6144;
      unsigned short* Ps = SMEM + 24576 + wave * 2048;

      if (kv0 <= q0 + 31) {  // wave has at least one unmasked element
        f32x4 st[4][2] = {};
        #pragma unroll
        for (int dk = 0; dk < 3; ++dk) {
          bf16x8 af[4];
          #pragma unroll
          for (int kb = 0; kb < 4; ++kb)
            af[kb] = ld_frag(&Ks[dk * 2048 + (kb * 16 + r) * 32 + ((g ^ ((r >> 1) & 3)) * 8)]);
          __builtin_amdgcn_s_setprio(1);
          #pragma unroll
          for (int kb = 0; kb < 4; ++kb)
            #pragma unroll
            for (int qb = 0; qb < 2; ++qb)
              st[kb][qb] = __builtin_amdgcn_mfma_f32_16x16x32_bf16(af[kb], qf[qb][dk], st[kb][qb], 0, 0, 0);
          __builtin_amdgcn_s_setprio(0);
        }
        // scale (exp2 domain) + causal mask (k_abs <= q_abs)
        if (kv0 + 63 > q0) {
          #pragma unroll
          for (int kb = 0; kb < 4; ++kb)
            #pragma unroll
            for (int qb = 0; qb < 2; ++qb)
              #pragma unroll
              for (int rr = 0; rr < 4; ++rr) {
                const int ka = kv0 + kb * 16 + g * 4 + rr;
                const int qa = q0 + qb * 16 + r;
                const float s = st[kb][qb][rr] * kLS;
                st[kb][qb][rr] = (ka <= qa) ? s : -1e30f;
              }
        } else {
          #pragma unroll
          for (int kb = 0; kb < 4; ++kb)
            #pragma unroll
            for (int qb = 0; qb < 2; ++qb)
              #pragma unroll
              for (int rr = 0; rr < 4; ++rr)
                st[kb][qb][rr] *= kLS;
        }
        // online softmax (exp2 domain), per lane = its q column; T13 exact defer
        #pragma unroll
        for (int qb = 0; qb < 2; ++qb) {
          float mx = st[0][qb][0];
          #pragma unroll
          for (int kb = 0; kb < 4; ++kb)
            #pragma unroll
            for (int rr = 0; rr < 4; ++rr) mx = fmaxf(mx, st[kb][qb][rr]);
          mx = fmaxf(mx, __shfl_xor(mx, 16));
          mx = fmaxf(mx, __shfl_xor(mx, 32));
          if (__all(mx <= m_[qb])) {
            float rs = 0.f;
            #pragma unroll
            for (int kb = 0; kb < 4; ++kb)
              #pragma unroll
              for (int rr = 0; rr < 4; ++rr) {
                const float p = __builtin_amdgcn_exp2f(st[kb][qb][rr] - m_[qb]);
                st[kb][qb][rr] = p;
                rs += p;
              }
            rs += __shfl_xor(rs, 16);
            rs += __shfl_xor(rs, 32);
            l_[qb] += rs;
          } else {
            const float mnew = fmaxf(m_[qb], mx);
            const float corr = __builtin_amdgcn_exp2f(m_[qb] - mnew);
            m_[qb] = mnew;
            float rs = 0.f;
            #pragma unroll
            for (int kb = 0; kb < 4; ++kb)
              #pragma unroll
              for (int rr = 0; rr < 4; ++rr) {
                const float p = __builtin_amdgcn_exp2f(st[kb][qb][rr] - mnew);
                st[kb][qb][rr] = p;
                rs += p;
              }
            rs += __shfl_xor(rs, 16);
            rs += __shfl_xor(rs, 32);
            l_[qb] = l_[qb] * corr + rs;
            #pragma unroll
            for (int db = 0; db < 6; ++db) o[db][qb] *= corr;
          }
        }
        // P[q][k] (bf16) to per-wave LDS, swizzled
        #pragma unroll
        for (int kb = 0; kb < 4; ++kb)
          #pragma unroll
          for (int qb = 0; qb < 2; ++qb) {
            u16x4 w;
            #pragma unroll
            for (int rr = 0; rr < 4; ++rr) w[rr] = f2bf(st[kb][qb][rr]);
            const int q = qb * 16 + r;
            *(u16x4*)&Ps[q * 64 + (((2 * kb + (g >> 1)) ^ (r & 7)) << 3) + (g & 1) * 4] = w;
          }
        // O^T += V^T * P^T
        #pragma unroll
        for (int kk = 0; kk < 2; ++kk) {
          bf16x8 pb[2];
          #pragma unroll
          for (int qb = 0; qb < 2; ++qb)
            pb[qb] = ld_frag(&Ps[(qb * 16 + r) * 64 + ((kk * 4 + g) ^ (r & 7)) * 8]);
          __builtin_amdgcn_s_setprio(1);
          #pragma unroll
          for (int db = 0; db < 6; ++db) {
            const bf16x8 va = ld_frag(&Vs[(db * 16 + r) * 64 + ((kk * 4 + g) ^ (r & 7)) * 8]);
            #pragma unroll
            for (int qb = 0; qb < 2; ++qb)
              o[db][qb] = __builtin_amdgcn_mfma_f32_16x16x32_bf16(va, pb[qb], o[db][qb], 0, 0, 0);
          }
          __builtin_amdgcn_s_setprio(0);
        }
      }
      __syncthreads();
    }

    // epilogue: normalize, transpose through LDS (per-wave region), coalesced stores
    const float inv_l[2] = {1.f / l_[0], 1.f / l_[1]};
    unsigned short* obuf = SMEM + wave * 3328;  // 32 x 104 per wave
    #pragma unroll
    for (int db = 0; db < 6; ++db)
      #pragma unroll
      for (int qb = 0; qb < 2; ++qb) {
        u16x4 w;
        #pragma unroll
        for (int rr = 0; rr < 4; ++rr) w[rr] = f2bf(o[db][qb][rr] * inv_l[qb]);
        *(u16x4*)&obuf[(qb * 16 + r) * 104 + db * 16 + g * 4] = w;
      }
    #pragma unroll
    for (int it = 0; it < 6; ++it) {
      const int cc = it * 64 + lane;
      const int qr = cc / 12, d0 = (cc % 12) * 8;
      *(u32x4*)&ctx[(size_t)(b * 2048 + q0 + qr) * 3072 + h * 96 + d0] =
          *(const u32x4*)&obuf[qr * 104 + d0];
    }
  }
}

extern "C" void kernel_launch(void* const* d_in, const int* in_sizes, int n_in,
                              void* d_out, int out_size, void* d_ws, size_t ws_size,
                              hipStream_t stream) {
  const float* hs   = (const float*)d_in[0];
  const float* cosp = (const float*)d_in[1];
  const float* sinp = (const float*)d_in[2];
  const float* wqkv = (const float*)d_in[4];
  const float* wo   = (const float*)d_in[5];
  float* out = (float*)d_out;

  // workspace layout (bf16 elems): qkv 18,874,368 | hsb 12,582,912 | wqb 14,155,776
  // after GEMM1: hsb region reused as vt (3,145,728) + wob (9,437,184); wqb as ctx.
  unsigned short* qkv = (unsigned short*)d_ws;
  unsigned short* hsb = qkv + 18874368;
  unsigned short* wqb = hsb + 12582912;
  unsigned short* vt  = hsb;
  unsigned short* wob = hsb + 3145728;
  unsigned short* ctx = wqb;

  cvt_bf16<<<12288, 256, 0, stream>>>(hs,   hsb, 3145728);
  cvt_bf16<<<13824, 256, 0, stream>>>(wqkv, wqb, 3538944);
  gemm3b<1><<<288, 512, 0, stream>>>(hsb, wqb, (void*)qkv, 4096, 4608, 3072);
  rope_qk<<<7680, 256, 0, stream>>>(qkv, cosp, sinp);
  vtrans<<<dim3(32, 8, 2), 256, 0, stream>>>(qkv, vt);
  cvt_bf16<<<9216, 256, 0, stream>>>(wo, wob, 2359296);
  attn_fwd<<<256, 512, 0, stream>>>(qkv, vt, ctx);
  gemm3b<0><<<192, 512, 0, stream>>>(ctx, wob, (void*)out, 4096, 3072, 3072);
}

// Round 11
// 367.773 us; speedup vs baseline: 1.1315x; 1.1315x over previous
//
#include <hip/hip_runtime.h>

typedef __attribute__((ext_vector_type(8))) __bf16 bf16x8;
typedef __attribute__((ext_vector_type(4))) float f32x4;
typedef __attribute__((ext_vector_type(4))) unsigned int u32x4;
typedef __attribute__((ext_vector_type(4))) unsigned short u16x4;
typedef __attribute__((ext_vector_type(8))) unsigned short u16x8;

__device__ __forceinline__ unsigned short f2bf(float x) {
  unsigned u = __builtin_bit_cast(unsigned, x);
  u += 0x7fffu + ((u >> 16) & 1u);
  return (unsigned short)(u >> 16);
}
__device__ __forceinline__ float bf2f(unsigned short h) {
  unsigned u = ((unsigned)h) << 16;
  return __builtin_bit_cast(float, u);
}
__device__ __forceinline__ bf16x8 ld_frag(const unsigned short* p) {
  u32x4 u = *(const u32x4*)p;
  return __builtin_bit_cast(bf16x8, u);
}
__device__ __forceinline__ void gload_lds16(const unsigned short* g, unsigned short* l) {
  __builtin_amdgcn_global_load_lds(
      (const __attribute__((address_space(1))) void*)g,
      (__attribute__((address_space(3))) void*)l, 16, 0, 0);
}

// ---------------- f32 -> bf16 conversion (vectorized) ----------------
__global__ __launch_bounds__(256) void cvt_bf16(const float* __restrict__ in,
                                                unsigned short* __restrict__ out, int n4) {
  int i = blockIdx.x * 256 + threadIdx.x;
  if (i >= n4) return;
  f32x4 v = *((const f32x4*)in + i);
  u16x4 o;
  #pragma unroll
  for (int j = 0; j < 4; ++j) o[j] = f2bf(v[j]);
  *((u16x4*)out + i) = o;
}

// ---------------- 8-phase GEMM: C[M,N] = A[M,K] * B[N,K]^T (r6/r9 proven) --------
template <int WRITE_BF16>
__global__ __launch_bounds__(512, 2) void gemm8p(const unsigned short* __restrict__ A,
                                                 const unsigned short* __restrict__ B,
                                                 void* __restrict__ Cv,
                                                 int M, int N, int K) {
  __shared__ __align__(16) unsigned short SM[57344];  // 112 KB
  const int nwg = gridDim.x;
  const int swz = (blockIdx.x & 7) * (nwg >> 3) + (blockIdx.x >> 3);
  const int bx = swz & 15, by = swz >> 4;      // M/256 == 16 for both GEMMs
  const int row0 = bx * 256, col0 = by * 192;
  const int tid = threadIdx.x;
  const int wave = tid >> 6, lane = tid & 63;
  const int g = lane >> 4, r = lane & 15;
  const int wm = (wave >> 2) * 128, wn = (wave & 3) * 48;
  const int NT = K >> 6;

  const unsigned short* Agb = A + (size_t)row0 * K;
  const unsigned short* Bgb = B + (size_t)col0 * K;

  f32x4 acc[8][3] = {};

  auto SU = [&](const unsigned short* src, unsigned short* dst, int u) {
    const int pos = u * 512 + tid;
    const int rw = pos >> 3, cc = pos & 7;
    gload_lds16(src + (size_t)rw * K + ((cc ^ (rw & 7)) * 8), dst + pos * 8);
  };
  auto LDA = [&](const unsigned short* base, int mi, int dk) {
    const int rw = wm + mi * 16 + r;
    return ld_frag(base + rw * 64 + (((dk * 4 + g) ^ (r & 7)) * 8));
  };
  auto LDB = [&](const unsigned short* base, int ni, int dk) {
    const int rw = wn + ni * 16 + r;
    return ld_frag(base + rw * 64 + (((dk * 4 + g) ^ (r & 7)) * 8));
  };

  SU(Agb, SM, 0); SU(Agb, SM, 1); SU(Agb, SM, 2); SU(Agb, SM, 3);
  SU(Bgb, SM + 16384, 0); SU(Bgb, SM + 16384, 1); SU(Bgb, SM + 16384, 2);
  __syncthreads();

  for (int t = 0; t < NT; ++t) {
    const int d = t & 1;
    const unsigned short* Ab = SM + d * 28672;
    const unsigned short* Bb = Ab + 16384;
    unsigned short* An = SM + (d ^ 1) * 28672;
    unsigned short* Bn = An + 16384;
    const unsigned short* Asrc = Agb + (t + 1) * 64;
    const unsigned short* Bsrc = Bgb + (t + 1) * 64;
    const bool pf = (t + 1 < NT);

    bf16x8 a[4], b0, b1, b2;

    b0 = LDB(Bb, 0, 0); b1 = LDB(Bb, 1, 0); b2 = LDB(Bb, 2, 0);
    a[0] = LDA(Ab, 0, 0); a[1] = LDA(Ab, 1, 0); a[2] = LDA(Ab, 2, 0); a[3] = LDA(Ab, 3, 0);
    if (pf) { SU(Asrc, An, 0); SU(Asrc, An, 1); SU(Asrc, An, 2); }
    __builtin_amdgcn_s_barrier();
    asm volatile("s_waitcnt lgkmcnt(0)" ::: "memory");
    __builtin_amdgcn_sched_barrier(0);
    __builtin_amdgcn_s_setprio(1);
    #pragma unroll
    for (int i = 0; i < 4; ++i) {
      acc[i][0] = __builtin_amdgcn_mfma_f32_16x16x32_bf16(a[i], b0, acc[i][0], 0, 0, 0);
      acc[i][1] = __builtin_amdgcn_mfma_f32_16x16x32_bf16(a[i], b1, acc[i][1], 0, 0, 0);
      acc[i][2] = __builtin_amdgcn_mfma_f32_16x16x32_bf16(a[i], b2, acc[i][2], 0, 0, 0);
    }
    __builtin_amdgcn_s_setprio(0);
    __builtin_amdgcn_s_barrier();

    a[0] = LDA(Ab, 4, 0); a[1] = LDA(Ab, 5, 0); a[2] = LDA(Ab, 6, 0); a[3] = LDA(Ab, 7, 0);
    if (pf) { SU(Asrc, An, 3); SU(Bsrc, Bn, 0); }
    __builtin_amdgcn_s_barrier();
    asm volatile("s_waitcnt lgkmcnt(0)" ::: "memory");
    __builtin_amdgcn_sched_barrier(0);
    __builtin_amdgcn_s_setprio(1);
    #pragma unroll
    for (int i = 0; i < 4; ++i) {
      acc[4 + i][0] = __builtin_amdgcn_mfma_f32_16x16x32_bf16(a[i], b0, acc[4 + i][0], 0, 0, 0);
      acc[4 + i][1] = __builtin_amdgcn_mfma_f32_16x16x32_bf16(a[i], b1, acc[4 + i][1], 0, 0, 0);
      acc[4 + i][2] = __builtin_amdgcn_mfma_f32_16x16x32_bf16(a[i], b2, acc[4 + i][2], 0, 0, 0);
    }
    __builtin_amdgcn_s_setprio(0);
    __builtin_amdgcn_s_barrier();

    b0 = LDB(Bb, 0, 1); b1 = LDB(Bb, 1, 1); b2 = LDB(Bb, 2, 1);
    a[0] = LDA(Ab, 0, 1); a[1] = LDA(Ab, 1, 1); a[2] = LDA(Ab, 2, 1); a[3] = LDA(Ab, 3, 1);
    if (pf) { SU(Bsrc, Bn, 1); SU(Bsrc, Bn, 2); }
    __builtin_amdgcn_s_barrier();
    asm volatile("s_waitcnt lgkmcnt(0)" ::: "memory");
    __builtin_amdgcn_sched_barrier(0);
    __builtin_amdgcn_s_setprio(1);
    #pragma unroll
    for (int i = 0; i < 4; ++i) {
      acc[i][0] = __builtin_amdgcn_mfma_f32_16x16x32_bf16(a[i], b0, acc[i][0], 0, 0, 0);
      acc[i][1] = __builtin_amdgcn_mfma_f32_16x16x32_bf16(a[i], b1, acc[i][1], 0, 0, 0);
      acc[i][2] = __builtin_amdgcn_mfma_f32_16x16x32_bf16(a[i], b2, acc[i][2], 0, 0, 0);
    }
    __builtin_amdgcn_s_setprio(0);
    __builtin_amdgcn_s_barrier();

    a[0] = LDA(Ab, 4, 1); a[1] = LDA(Ab, 5, 1); a[2] = LDA(Ab, 6, 1); a[3] = LDA(Ab, 7, 1);
    __builtin_amdgcn_s_barrier();
    asm volatile("s_waitcnt lgkmcnt(0)" ::: "memory");
    __builtin_amdgcn_sched_barrier(0);
    __builtin_amdgcn_s_setprio(1);
    #pragma unroll
    for (int i = 0; i < 4; ++i) {
      acc[4 + i][0] = __builtin_amdgcn_mfma_f32_16x16x32_bf16(a[i], b0, acc[4 + i][0], 0, 0, 0);
      acc[4 + i][1] = __builtin_amdgcn_mfma_f32_16x16x32_bf16(a[i], b1, acc[4 + i][1], 0, 0, 0);
      acc[4 + i][2] = __builtin_amdgcn_mfma_f32_16x16x32_bf16(a[i], b2, acc[4 + i][2], 0, 0, 0);
    }
    __builtin_amdgcn_s_setprio(0);
    asm volatile("s_waitcnt vmcnt(0)" ::: "memory");
    __builtin_amdgcn_s_barrier();
  }

  #pragma unroll
  for (int mi = 0; mi < 8; ++mi)
    #pragma unroll
    for (int n = 0; n < 3; ++n)
      #pragma unroll
      for (int rr = 0; rr < 4; ++rr) {
        const size_t idx = (size_t)(row0 + wm + mi * 16 + g * 4 + rr) * (size_t)N
                         + (col0 + wn + n * 16 + r);
        if (WRITE_BF16) ((unsigned short*)Cv)[idx] = f2bf(acc[mi][n][rr]);
        else            ((float*)Cv)[idx] = acc[mi][n][rr];
      }
}

// ---------------- RoPE in-place on Q+K, vectorized (4 d-elems/thread) ----------------
__global__ __launch_bounds__(256) void rope_qk(unsigned short* __restrict__ qkv,
                                               const float* __restrict__ cs,
                                               const float* __restrict__ sn) {
  const int t = blockIdx.x * 256 + threadIdx.x;  // B*S*40*12 = 1,966,080 exact
  const int d4 = t % 12;
  const int rest = t / 12;
  const int head = rest % 40;
  const int row = rest / 40;                     // b*2048+s
  const size_t base = (size_t)row * 4608 + head * 96 + d4 * 4;
  const u16x4 a = *(const u16x4*)&qkv[base];
  const u16x4 bq = *(const u16x4*)&qkv[base + 48];
  const int cb = row * 96 + d4 * 4;
  const f32x4 c1 = *(const f32x4*)&cs[cb];
  const f32x4 s1 = *(const f32x4*)&sn[cb];
  const f32x4 c2 = *(const f32x4*)&cs[cb + 48];
  const f32x4 s2 = *(const f32x4*)&sn[cb + 48];
  u16x4 o1, o2;
  #pragma unroll
  for (int j = 0; j < 4; ++j) {
    const float x1 = bf2f(a[j]), x2 = bf2f(bq[j]);
    o1[j] = f2bf(x1 * c1[j] - x2 * s1[j]);
    o2[j] = f2bf(x2 * c2[j] + x1 * s2[j]);
  }
  *(u16x4*)&qkv[base] = o1;
  *(u16x4*)&qkv[base + 48] = o2;
}

// ---------------- V transpose: qkv[b,s,3840+kvh*96+d] -> vt[b,kvh,d,s] ----------------
__global__ __launch_bounds__(256) void vtrans(const unsigned short* __restrict__ qkv,
                                              unsigned short* __restrict__ vt) {
  __shared__ __align__(16) unsigned short T[64 * 104];
  const int s0 = blockIdx.x * 64;
  const int kvh = blockIdx.y, b = blockIdx.z;
  const int tid = threadIdx.x;
  #pragma unroll
  for (int it = 0; it < 3; ++it) {
    const int c = it * 256 + tid;
    const int sr = c / 12, d0 = (c % 12) * 8;
    *(u32x4*)&T[sr * 104 + d0] =
        *(const u32x4*)&qkv[(size_t)(b * 2048 + s0 + sr) * 4608 + 3840 + kvh * 96 + d0];
  }
  __syncthreads();
  #pragma unroll
  for (int it = 0; it < 3; ++it) {
    const int c = it * 256 + tid;
    const int dr = c >> 3, k0 = (c & 7) * 8;
    u16x8 o;
    #pragma unroll
    for (int j = 0; j < 8; ++j) o[j] = T[(k0 + j) * 104 + dr];
    *(u16x8*)&vt[((size_t)(b * 8 + kvh) * 96 + dr) * 2048 + s0 + k0] = o;
  }
}

// ---------------- Flash attention, causal GQA, swapped QK^T ----------------
// r11: 8 waves x 16 q-rows (q-tile 128/block) to cut VGPR <= 128 so 512-thr
// blocks go 2/CU = 16 waves/CU (LDS 64KB). Grid 512 uniform blocks via
// fold-pair {15-pr, pr} over 128-row q-tiles (34 tile-units each); XCD decode
// keeps 32 blocks per (b,kvh) on one XCD. Staging/swizzles proven from r9.
__global__ __launch_bounds__(512) void attn_fwd(const unsigned short* __restrict__ qkv,
                                                const unsigned short* __restrict__ vt,
                                                unsigned short* __restrict__ ctx) {
  __shared__ __align__(16) unsigned short SMEM[32768];  // 64 KB
  const int wg = blockIdx.x;             // 0..511
  const int xcd = wg & 7, j = wg >> 3;   // j 0..63
  const int c = xcd + ((j >> 5) << 3);   // (b,kvh) id, 0..15
  const int b = c >> 3, kvh = c & 7;
  const int rj = j & 31;
  const int h = kvh * 4 + (rj >> 3);
  const int pr = rj & 7;                 // fold pair: qt in {15-pr, pr}
  const int tid = threadIdx.x;
  const int wave = tid >> 6, lane = tid & 63;
  const int g = lane >> 4, r = lane & 15;
  const float kLS = 0.14724445f;         // (1/sqrt(96)) * log2(e)

  const unsigned short* kgbase = qkv + (size_t)(b * 2048) * 4608 + 3072 + kvh * 96;
  const unsigned short* vgbase = vt + (size_t)(b * 8 + kvh) * 96 * 2048;

  // STAGE tile t into buffer bi: K 768 + V 768 chunks, 3 iters x 512 thr
  auto STAGE = [&](int t, int bi) {
    const int kv0 = t * 64;
    unsigned short* kd = SMEM + bi * 6144;
    unsigned short* vd = SMEM + 12288 + bi * 6144;
    #pragma unroll
    for (int i = 0; i < 3; ++i) {
      const int l = i * 512 + tid;
      if (l < 768) {  // K: [dk][row][c], src chunk c^((row>>1)&3)
        const int dk = l >> 8, rem = l & 255;
        const int row = rem >> 2, cc = rem & 3;
        const int csrc = cc ^ ((row >> 1) & 3);
        gload_lds16(kgbase + (size_t)(kv0 + row) * 4608 + dk * 32 + csrc * 8, kd + l * 8);
      } else {        // V: [row][c], src chunk c^(row&7)
        const int lv = l - 768;
        const int row = lv >> 3, cc = lv & 7;
        const int csrc = cc ^ (row & 7);
        gload_lds16(vgbase + (size_t)row * 2048 + kv0 + csrc * 8, vd + lv * 8);
      }
    }
  };

  #pragma unroll 1
  for (int sel = 0; sel < 2; ++sel) {
    const int qt = sel ? pr : 15 - pr;
    const int nt = qt * 2 + 2;
    const int q0 = qt * 128 + wave * 16;

    __syncthreads();   // protect LDS (prev epilogue reads) before re-staging

    bf16x8 qf[3];
    #pragma unroll
    for (int dk = 0; dk < 3; ++dk)
      qf[dk] = ld_frag(&qkv[(size_t)(b * 2048 + q0 + r) * 4608 + h * 96 + dk * 32 + g * 8]);

    f32x4 o[6] = {};
    float m_ = -1e30f;
    float l_ = 0.f;

    STAGE(0, 0);
    __syncthreads();

    for (int t = 0; t < nt; ++t) {
      const int cur = t & 1;
      if (t + 1 < nt) STAGE(t + 1, cur ^ 1);
      const int kv0 = t * 64;
      const unsigned short* Ks = SMEM + cur * 6144;
      const unsigned short* Vs = SMEM + 12288 + cur * 6144;
      unsigned short* Ps = SMEM + 24576 + wave * 1024;

      if (kv0 <= q0 + 15) {  // wave has at least one unmasked element
        f32x4 st[4] = {};
        #pragma unroll
        for (int dk = 0; dk < 3; ++dk) {
          bf16x8 af[4];
          #pragma unroll
          for (int kb = 0; kb < 4; ++kb)
            af[kb] = ld_frag(&Ks[dk * 2048 + (kb * 16 + r) * 32 + ((g ^ ((r >> 1) & 3)) * 8)]);
          __builtin_amdgcn_s_setprio(1);
          #pragma unroll
          for (int kb = 0; kb < 4; ++kb)
            st[kb] = __builtin_amdgcn_mfma_f32_16x16x32_bf16(af[kb], qf[dk], st[kb], 0, 0, 0);
          __builtin_amdgcn_s_setprio(0);
        }
        // scale (exp2 domain) + causal mask (k_abs <= q_abs)
        if (kv0 + 63 > q0) {
          #pragma unroll
          for (int kb = 0; kb < 4; ++kb)
            #pragma unroll
            for (int rr = 0; rr < 4; ++rr) {
              const int ka = kv0 + kb * 16 + g * 4 + rr;
              const int qa = q0 + r;
              const float s = st[kb][rr] * kLS;
              st[kb][rr] = (ka <= qa) ? s : -1e30f;
            }
        } else {
          #pragma unroll
          for (int kb = 0; kb < 4; ++kb)
            #pragma unroll
            for (int rr = 0; rr < 4; ++rr)
              st[kb][rr] *= kLS;
        }
        // online softmax (exp2 domain), per lane = its q column; T13 exact defer
        {
          float mx = st[0][0];
          #pragma unroll
          for (int kb = 0; kb < 4; ++kb)
            #pragma unroll
            for (int rr = 0; rr < 4; ++rr) mx = fmaxf(mx, st[kb][rr]);
          mx = fmaxf(mx, __shfl_xor(mx, 16));
          mx = fmaxf(mx, __shfl_xor(mx, 32));
          if (__all(mx <= m_)) {
            float rs = 0.f;
            #pragma unroll
            for (int kb = 0; kb < 4; ++kb)
              #pragma unroll
              for (int rr = 0; rr < 4; ++rr) {
                const float p = __builtin_amdgcn_exp2f(st[kb][rr] - m_);
                st[kb][rr] = p;
                rs += p;
              }
            rs += __shfl_xor(rs, 16);
            rs += __shfl_xor(rs, 32);
            l_ += rs;
          } else {
            const float mnew = fmaxf(m_, mx);
            const float corr = __builtin_amdgcn_exp2f(m_ - mnew);
            m_ = mnew;
            float rs = 0.f;
            #pragma unroll
            for (int kb = 0; kb < 4; ++kb)
              #pragma unroll
              for (int rr = 0; rr < 4; ++rr) {
                const float p = __builtin_amdgcn_exp2f(st[kb][rr] - mnew);
                st[kb][rr] = p;
                rs += p;
              }
            rs += __shfl_xor(rs, 16);
            rs += __shfl_xor(rs, 32);
            l_ = l_ * corr + rs;
            #pragma unroll
            for (int db = 0; db < 6; ++db) o[db] *= corr;
          }
        }
        // P[q][k] (bf16) to per-wave LDS, swizzled (16 rows x 64 k)
        #pragma unroll
        for (int kb = 0; kb < 4; ++kb) {
          u16x4 w;
          #pragma unroll
          for (int rr = 0; rr < 4; ++rr) w[rr] = f2bf(st[kb][rr]);
          *(u16x4*)&Ps[r * 64 + (((2 * kb + (g >> 1)) ^ (r & 7)) << 3) + (g & 1) * 4] = w;
        }
        // O^T += V^T * P^T
        #pragma unroll
        for (int kk = 0; kk < 2; ++kk) {
          const bf16x8 pb = ld_frag(&Ps[r * 64 + ((kk * 4 + g) ^ (r & 7)) * 8]);
          __builtin_amdgcn_s_setprio(1);
          #pragma unroll
          for (int db = 0; db < 6; ++db) {
            const bf16x8 va = ld_frag(&Vs[(db * 16 + r) * 64 + ((kk * 4 + g) ^ (r & 7)) * 8]);
            o[db] = __builtin_amdgcn_mfma_f32_16x16x32_bf16(va, pb, o[db], 0, 0, 0);
          }
          __builtin_amdgcn_s_setprio(0);
        }
      }
      __syncthreads();
    }

    // epilogue: normalize, transpose through LDS (per-wave region), coalesced stores
    const float inv_l = 1.f / l_;
    unsigned short* obuf = SMEM + wave * 1664;  // 16 x 104 per wave
    #pragma unroll
    for (int db = 0; db < 6; ++db) {
      u16x4 w;
      #pragma unroll
      for (int rr = 0; rr < 4; ++rr) w[rr] = f2bf(o[db][rr] * inv_l);
      *(u16x4*)&obuf[r * 104 + db * 16 + g * 4] = w;
    }
    #pragma unroll
    for (int it = 0; it < 3; ++it) {
      const int cc = it * 64 + lane;
      const int qr = cc / 12, d0 = (cc % 12) * 8;
      *(u32x4*)&ctx[(size_t)(b * 2048 + qt * 128 + wave * 16 + qr) * 3072 + h * 96 + d0] =
          *(const u32x4*)&obuf[qr * 104 + d0];
    }
  }
}

extern "C" void kernel_launch(void* const* d_in, const int* in_sizes, int n_in,
                              void* d_out, int out_size, void* d_ws, size_t ws_size,
                              hipStream_t stream) {
  const float* hs   = (const float*)d_in[0];
  const float* cosp = (const float*)d_in[1];
  const float* sinp = (const float*)d_in[2];
  const float* wqkv = (const float*)d_in[4];
  const float* wo   = (const float*)d_in[5];
  float* out = (float*)d_out;

  // workspace layout (bf16 elems): qkv 18,874,368 | hsb 12,582,912 | wqb 14,155,776
  // after GEMM1: hsb region reused as vt (3,145,728) + wob (9,437,184); wqb as ctx.
  unsigned short* qkv = (unsigned short*)d_ws;
  unsigned short* hsb = qkv + 18874368;
  unsigned short* wqb = hsb + 12582912;
  unsigned short* vt  = hsb;
  unsigned short* wob = hsb + 3145728;
  unsigned short* ctx = wqb;

  cvt_bf16<<<12288, 256, 0, stream>>>(hs,   hsb, 3145728);
  cvt_bf16<<<13824, 256, 0, stream>>>(wqkv, wqb, 3538944);
  gemm8p<1><<<384, 512, 0, stream>>>(hsb, wqb, (void*)qkv, 4096, 4608, 3072);
  rope_qk<<<7680, 256, 0, stream>>>(qkv, cosp, sinp);
  vtrans<<<dim3(32, 8, 2), 256, 0, stream>>>(qkv, vt);
  cvt_bf16<<<9216, 256, 0, stream>>>(wo, wob, 2359296);
  attn_fwd<<<512, 512, 0, stream>>>(qkv, vt, ctx);
  gemm8p<0><<<256, 512, 0, stream>>>(ctx, wob, (void*)out, 4096, 3072, 3072);
}

// Round 12
// 342.319 us; speedup vs baseline: 1.2157x; 1.0744x over previous
//
#include <hip/hip_runtime.h>

typedef __attribute__((ext_vector_type(8))) __bf16 bf16x8;
typedef __attribute__((ext_vector_type(4))) float f32x4;
typedef __attribute__((ext_vector_type(4))) unsigned int u32x4;
typedef __attribute__((ext_vector_type(4))) unsigned short u16x4;
typedef __attribute__((ext_vector_type(8))) unsigned short u16x8;

__device__ __forceinline__ unsigned short f2bf(float x) {
  unsigned u = __builtin_bit_cast(unsigned, x);
  u += 0x7fffu + ((u >> 16) & 1u);
  return (unsigned short)(u >> 16);
}
__device__ __forceinline__ float bf2f(unsigned short h) {
  unsigned u = ((unsigned)h) << 16;
  return __builtin_bit_cast(float, u);
}
__device__ __forceinline__ bf16x8 ld_frag(const unsigned short* p) {
  u32x4 u = *(const u32x4*)p;
  return __builtin_bit_cast(bf16x8, u);
}
__device__ __forceinline__ void gload_lds16(const unsigned short* g, unsigned short* l) {
  __builtin_amdgcn_global_load_lds(
      (const __attribute__((address_space(1))) void*)g,
      (__attribute__((address_space(3))) void*)l, 16, 0, 0);
}

// ---------------- f32 -> bf16 conversion (vectorized) ----------------
__global__ __launch_bounds__(256) void cvt_bf16(const float* __restrict__ in,
                                                unsigned short* __restrict__ out, int n4) {
  int i = blockIdx.x * 256 + threadIdx.x;
  if (i >= n4) return;
  f32x4 v = *((const f32x4*)in + i);
  u16x4 o;
  #pragma unroll
  for (int j = 0; j < 4; ++j) o[j] = f2bf(v[j]);
  *((u16x4*)out + i) = o;
}

// ---- 8-phase GEMM, 4M x 2N wave map (each wave owns a full 96-col head) ----
// C[M,N] = A[M,K]*B[N,K]^T. BM=256,BN=192,BK=64; 512thr = 8 waves (4M x 2N),
// per-wave 64x96 (acc[4][6]); 20 ds_read per K-tile per wave vs 22 (ratio up).
// MODE 0: f32 C (gemm2). MODE 1: bf16 C + fused RoPE on heads < 3840 (gemm1) —
// rotate-half partner (d, d+48) = (acc[mi][n], acc[mi][n+3]) is thread-local.
template <int MODE>
__global__ __launch_bounds__(512, 2) void gemm8p(const unsigned short* __restrict__ A,
                                                 const unsigned short* __restrict__ B,
                                                 void* __restrict__ Cv,
                                                 const float* __restrict__ cs,
                                                 const float* __restrict__ sn,
                                                 int M, int N, int K) {
  __shared__ __align__(16) unsigned short SM[57344];  // 112 KB
  const int nwg = gridDim.x;
  const int swz = (blockIdx.x & 7) * (nwg >> 3) + (blockIdx.x >> 3);
  const int bx = swz & 15, by = swz >> 4;      // M/256 == 16 for both GEMMs
  const int row0 = bx * 256, col0 = by * 192;
  const int tid = threadIdx.x;
  const int wave = tid >> 6, lane = tid & 63;
  const int g = lane >> 4, r = lane & 15;
  const int wm = (wave >> 1) * 64, wn = (wave & 1) * 96;
  const int NT = K >> 6;

  const unsigned short* Agb = A + (size_t)row0 * K;
  const unsigned short* Bgb = B + (size_t)col0 * K;

  f32x4 acc[4][6] = {};

  auto SU = [&](const unsigned short* src, unsigned short* dst, int u) {
    const int pos = u * 512 + tid;
    const int rw = pos >> 3, cc = pos & 7;
    gload_lds16(src + (size_t)rw * K + ((cc ^ (rw & 7)) * 8), dst + pos * 8);
  };
  auto LDA = [&](const unsigned short* base, int mi, int dk) {
    const int rw = wm + mi * 16 + r;
    return ld_frag(base + rw * 64 + (((dk * 4 + g) ^ (r & 7)) * 8));
  };
  auto LDB = [&](const unsigned short* base, int ni, int dk) {
    const int rw = wn + ni * 16 + r;
    return ld_frag(base + rw * 64 + (((dk * 4 + g) ^ (r & 7)) * 8));
  };

  SU(Agb, SM, 0); SU(Agb, SM, 1); SU(Agb, SM, 2); SU(Agb, SM, 3);
  SU(Bgb, SM + 16384, 0); SU(Bgb, SM + 16384, 1); SU(Bgb, SM + 16384, 2);
  __syncthreads();

  for (int t = 0; t < NT; ++t) {
    const int d = t & 1;
    const unsigned short* Ab = SM + d * 28672;
    const unsigned short* Bb = Ab + 16384;
    unsigned short* An = SM + (d ^ 1) * 28672;
    unsigned short* Bn = An + 16384;
    const unsigned short* Asrc = Agb + (t + 1) * 64;
    const unsigned short* Bsrc = Bgb + (t + 1) * 64;
    const bool pf = (t + 1 < NT);

    bf16x8 a0, a1, b[6];

    // ---- ph0: dk=0, mi 0-1 (B dk0 loaded, held through ph1) ----
    b[0] = LDB(Bb, 0, 0); b[1] = LDB(Bb, 1, 0); b[2] = LDB(Bb, 2, 0);
    b[3] = LDB(Bb, 3, 0); b[4] = LDB(Bb, 4, 0); b[5] = LDB(Bb, 5, 0);
    a0 = LDA(Ab, 0, 0); a1 = LDA(Ab, 1, 0);
    if (pf) { SU(Asrc, An, 0); SU(Asrc, An, 1); SU(Asrc, An, 2); }
    __builtin_amdgcn_s_barrier();
    asm volatile("s_waitcnt lgkmcnt(0)" ::: "memory");
    __builtin_amdgcn_sched_barrier(0);
    __builtin_amdgcn_s_setprio(1);
    #pragma unroll
    for (int n = 0; n < 6; ++n) {
      acc[0][n] = __builtin_amdgcn_mfma_f32_16x16x32_bf16(a0, b[n], acc[0][n], 0, 0, 0);
      acc[1][n] = __builtin_amdgcn_mfma_f32_16x16x32_bf16(a1, b[n], acc[1][n], 0, 0, 0);
    }
    __builtin_amdgcn_s_setprio(0);
    __builtin_amdgcn_s_barrier();

    // ---- ph1: dk=0, mi 2-3 ----
    a0 = LDA(Ab, 2, 0); a1 = LDA(Ab, 3, 0);
    if (pf) { SU(Asrc, An, 3); SU(Bsrc, Bn, 0); }
    __builtin_amdgcn_s_barrier();
    asm volatile("s_waitcnt lgkmcnt(0)" ::: "memory");
    __builtin_amdgcn_sched_barrier(0);
    __builtin_amdgcn_s_setprio(1);
    #pragma unroll
    for (int n = 0; n < 6; ++n) {
      acc[2][n] = __builtin_amdgcn_mfma_f32_16x16x32_bf16(a0, b[n], acc[2][n], 0, 0, 0);
      acc[3][n] = __builtin_amdgcn_mfma_f32_16x16x32_bf16(a1, b[n], acc[3][n], 0, 0, 0);
    }
    __builtin_amdgcn_s_setprio(0);
    __builtin_amdgcn_s_barrier();

    // ---- ph2: dk=1, mi 0-1 ----
    b[0] = LDB(Bb, 0, 1); b[1] = LDB(Bb, 1, 1); b[2] = LDB(Bb, 2, 1);
    b[3] = LDB(Bb, 3, 1); b[4] = LDB(Bb, 4, 1); b[5] = LDB(Bb, 5, 1);
    a0 = LDA(Ab, 0, 1); a1 = LDA(Ab, 1, 1);
    if (pf) { SU(Bsrc, Bn, 1); SU(Bsrc, Bn, 2); }
    __builtin_amdgcn_s_barrier();
    asm volatile("s_waitcnt lgkmcnt(0)" ::: "memory");
    __builtin_amdgcn_sched_barrier(0);
    __builtin_amdgcn_s_setprio(1);
    #pragma unroll
    for (int n = 0; n < 6; ++n) {
      acc[0][n] = __builtin_amdgcn_mfma_f32_16x16x32_bf16(a0, b[n], acc[0][n], 0, 0, 0);
      acc[1][n] = __builtin_amdgcn_mfma_f32_16x16x32_bf16(a1, b[n], acc[1][n], 0, 0, 0);
    }
    __builtin_amdgcn_s_setprio(0);
    __builtin_amdgcn_s_barrier();

    // ---- ph3: dk=1, mi 2-3 ----
    a0 = LDA(Ab, 2, 1); a1 = LDA(Ab, 3, 1);
    __builtin_amdgcn_s_barrier();
    asm volatile("s_waitcnt lgkmcnt(0)" ::: "memory");
    __builtin_amdgcn_sched_barrier(0);
    __builtin_amdgcn_s_setprio(1);
    #pragma unroll
    for (int n = 0; n < 6; ++n) {
      acc[2][n] = __builtin_amdgcn_mfma_f32_16x16x32_bf16(a0, b[n], acc[2][n], 0, 0, 0);
      acc[3][n] = __builtin_amdgcn_mfma_f32_16x16x32_bf16(a1, b[n], acc[3][n], 0, 0, 0);
    }
    __builtin_amdgcn_s_setprio(0);
    asm volatile("s_waitcnt vmcnt(0)" ::: "memory");
    __builtin_amdgcn_s_barrier();
  }

  // ---- epilogue ----
  if (MODE == 0) {
    float* outp = (float*)Cv;
    #pragma unroll
    for (int mi = 0; mi < 4; ++mi)
      #pragma unroll
      for (int n = 0; n < 6; ++n)
        #pragma unroll
        for (int rr = 0; rr < 4; ++rr) {
          const size_t idx = (size_t)(row0 + wm + mi * 16 + g * 4 + rr) * (size_t)N
                           + (col0 + wn + n * 16 + r);
          outp[idx] = acc[mi][n][rr];
        }
  } else {
    unsigned short* outp = (unsigned short*)Cv;
    const int hc0 = col0 + wn;               // head-aligned (multiple of 96)
    if (hc0 < 3840) {                        // Q or K head: fused RoPE
      #pragma unroll
      for (int mi = 0; mi < 4; ++mi)
        #pragma unroll
        for (int rr = 0; rr < 4; ++rr) {
          const int row = row0 + wm + mi * 16 + g * 4 + rr;
          const int cb = row * 96;
          const size_t rb = (size_t)row * N + hc0;
          #pragma unroll
          for (int n = 0; n < 3; ++n) {
            const int d = n * 16 + r;
            const float x1 = acc[mi][n][rr], x2 = acc[mi][n + 3][rr];
            const float c1 = cs[cb + d], s1 = sn[cb + d];
            const float c2 = cs[cb + d + 48], s2 = sn[cb + d + 48];
            outp[rb + d]      = f2bf(x1 * c1 - x2 * s1);
            outp[rb + d + 48] = f2bf(x2 * c2 + x1 * s2);
          }
        }
    } else {                                 // V head: plain bf16
      #pragma unroll
      for (int mi = 0; mi < 4; ++mi)
        #pragma unroll
        for (int n = 0; n < 6; ++n)
          #pragma unroll
          for (int rr = 0; rr < 4; ++rr) {
            const size_t idx = (size_t)(row0 + wm + mi * 16 + g * 4 + rr) * (size_t)N
                             + (col0 + wn + n * 16 + r);
            outp[idx] = f2bf(acc[mi][n][rr]);
          }
    }
  }
}

// ---------------- V transpose: qkv[b,s,3840+kvh*96+d] -> vt[b,kvh,d,s] ----------------
__global__ __launch_bounds__(256) void vtrans(const unsigned short* __restrict__ qkv,
                                              unsigned short* __restrict__ vt) {
  __shared__ __align__(16) unsigned short T[64 * 104];
  const int s0 = blockIdx.x * 64;
  const int kvh = blockIdx.y, b = blockIdx.z;
  const int tid = threadIdx.x;
  #pragma unroll
  for (int it = 0; it < 3; ++it) {
    const int c = it * 256 + tid;
    const int sr = c / 12, d0 = (c % 12) * 8;
    *(u32x4*)&T[sr * 104 + d0] =
        *(const u32x4*)&qkv[(size_t)(b * 2048 + s0 + sr) * 4608 + 3840 + kvh * 96 + d0];
  }
  __syncthreads();
  #pragma unroll
  for (int it = 0; it < 3; ++it) {
    const int c = it * 256 + tid;
    const int dr = c >> 3, k0 = (c & 7) * 8;
    u16x8 o;
    #pragma unroll
    for (int j = 0; j < 8; ++j) o[j] = T[(k0 + j) * 104 + dr];
    *(u16x8*)&vt[((size_t)(b * 8 + kvh) * 96 + dr) * 2048 + s0 + k0] = o;
  }
}

// ---------------- Flash attention, causal GQA, swapped QK^T (r9 exact) ----------------
__global__ __launch_bounds__(512) void attn_fwd(const unsigned short* __restrict__ qkv,
                                                const unsigned short* __restrict__ vt,
                                                unsigned short* __restrict__ ctx) {
  __shared__ __align__(16) unsigned short SMEM[40960];  // 80 KB
  const int wg = blockIdx.x;             // 0..255
  const int xcd = wg & 7, j = wg >> 3;   // j 0..31
  const int c = xcd + ((j >> 4) << 3);   // (b,kvh) id, 0..15
  const int b = c >> 3, kvh = c & 7;
  const int rj = j & 15;
  const int h = kvh * 4 + (rj >> 2);
  const int pr = rj & 3;                 // fold pair: qt in {7-pr, pr}
  const int tid = threadIdx.x;
  const int wave = tid >> 6, lane = tid & 63;
  const int g = lane >> 4, r = lane & 15;
  const float kLS = 0.14724445f;         // (1/sqrt(96)) * log2(e)

  const unsigned short* kgbase = qkv + (size_t)(b * 2048) * 4608 + 3072 + kvh * 96;
  const unsigned short* vgbase = vt + (size_t)(b * 8 + kvh) * 96 * 2048;

  auto STAGE = [&](int t, int bi) {
    const int kv0 = t * 64;
    unsigned short* kd = SMEM + bi * 6144;
    unsigned short* vd = SMEM + 12288 + bi * 6144;
    #pragma unroll
    for (int i = 0; i < 3; ++i) {
      const int l = i * 512 + tid;
      if (l < 768) {  // K: [dk][row][c], src chunk c^((row>>1)&3)
        const int dk = l >> 8, rem = l & 255;
        const int row = rem >> 2, cc = rem & 3;
        const int csrc = cc ^ ((row >> 1) & 3);
        gload_lds16(kgbase + (size_t)(kv0 + row) * 4608 + dk * 32 + csrc * 8, kd + l * 8);
      } else {        // V: [row][c], src chunk c^(row&7)
        const int lv = l - 768;
        const int row = lv >> 3, cc = lv & 7;
        const int csrc = cc ^ (row & 7);
        gload_lds16(vgbase + (size_t)row * 2048 + kv0 + csrc * 8, vd + lv * 8);
      }
    }
  };

  #pragma unroll 1
  for (int sel = 0; sel < 2; ++sel) {
    const int qt = sel ? pr : 7 - pr;
    const int nt = qt * 4 + 4;
    const int q0 = qt * 256 + wave * 32;

    __syncthreads();   // protect LDS (prev epilogue reads) before re-staging

    bf16x8 qf[2][3];
    #pragma unroll
    for (int qb = 0; qb < 2; ++qb)
      #pragma unroll
      for (int dk = 0; dk < 3; ++dk)
        qf[qb][dk] = ld_frag(&qkv[(size_t)(b * 2048 + q0 + qb * 16 + r) * 4608 + h * 96 + dk * 32 + g * 8]);

    f32x4 o[6][2] = {};
    float m_[2] = {-1e30f, -1e30f};
    float l_[2] = {0.f, 0.f};

    STAGE(0, 0);
    __syncthreads();

    for (int t = 0; t < nt; ++t) {
      const int cur = t & 1;
      if (t + 1 < nt) STAGE(t + 1, cur ^ 1);
      const int kv0 = t * 64;
      const unsigned short* Ks = SMEM + cur * 6144;
      const unsigned short* Vs = SMEM + 12288 + cur * 6144;
      unsigned short* Ps = SMEM + 24576 + wave * 2048;

      if (kv0 <= q0 + 31) {  // wave has at least one unmasked element
        f32x4 st[4][2] = {};
        #pragma unroll
        for (int dk = 0; dk < 3; ++dk) {
          bf16x8 af[4];
          #pragma unroll
          for (int kb = 0; kb < 4; ++kb)
            af[kb] = ld_frag(&Ks[dk * 2048 + (kb * 16 + r) * 32 + ((g ^ ((r >> 1) & 3)) * 8)]);
          __builtin_amdgcn_s_setprio(1);
          #pragma unroll
          for (int kb = 0; kb < 4; ++kb)
            #pragma unroll
            for (int qb = 0; qb < 2; ++qb)
              st[kb][qb] = __builtin_amdgcn_mfma_f32_16x16x32_bf16(af[kb], qf[qb][dk], st[kb][qb], 0, 0, 0);
          __builtin_amdgcn_s_setprio(0);
        }
        // scale (exp2 domain) + causal mask (k_abs <= q_abs)
        if (kv0 + 63 > q0) {
          #pragma unroll
          for (int kb = 0; kb < 4; ++kb)
            #pragma unroll
            for (int qb = 0; qb < 2; ++qb)
              #pragma unroll
              for (int rr = 0; rr < 4; ++rr) {
                const int ka = kv0 + kb * 16 + g * 4 + rr;
                const int qa = q0 + qb * 16 + r;
                const float s = st[kb][qb][rr] * kLS;
                st[kb][qb][rr] = (ka <= qa) ? s : -1e30f;
              }
        } else {
          #pragma unroll
          for (int kb = 0; kb < 4; ++kb)
            #pragma unroll
            for (int qb = 0; qb < 2; ++qb)
              #pragma unroll
              for (int rr = 0; rr < 4; ++rr)
                st[kb][qb][rr] *= kLS;
        }
        // online softmax (exp2 domain), per lane = its q column; T13 exact defer
        #pragma unroll
        for (int qb = 0; qb < 2; ++qb) {
          float mx = st[0][qb][0];
          #pragma unroll
          for (int kb = 0; kb < 4; ++kb)
            #pragma unroll
            for (int rr = 0; rr < 4; ++rr) mx = fmaxf(mx, st[kb][qb][rr]);
          mx = fmaxf(mx, __shfl_xor(mx, 16));
          mx = fmaxf(mx, __shfl_xor(mx, 32));
          if (__all(mx <= m_[qb])) {
            float rs = 0.f;
            #pragma unroll
            for (int kb = 0; kb < 4; ++kb)
              #pragma unroll
              for (int rr = 0; rr < 4; ++rr) {
                const float p = __builtin_amdgcn_exp2f(st[kb][qb][rr] - m_[qb]);
                st[kb][qb][rr] = p;
                rs += p;
              }
            rs += __shfl_xor(rs, 16);
            rs += __shfl_xor(rs, 32);
            l_[qb] += rs;
          } else {
            const float mnew = fmaxf(m_[qb], mx);
            const float corr = __builtin_amdgcn_exp2f(m_[qb] - mnew);
            m_[qb] = mnew;
            float rs = 0.f;
            #pragma unroll
            for (int kb = 0; kb < 4; ++kb)
              #pragma unroll
              for (int rr = 0; rr < 4; ++rr) {
                const float p = __builtin_amdgcn_exp2f(st[kb][qb][rr] - mnew);
                st[kb][qb][rr] = p;
                rs += p;
              }
            rs += __shfl_xor(rs, 16);
            rs += __shfl_xor(rs, 32);
            l_[qb] = l_[qb] * corr + rs;
            #pragma unroll
            for (int db = 0; db < 6; ++db) o[db][qb] *= corr;
          }
        }
        // P[q][k] (bf16) to per-wave LDS, swizzled
        #pragma unroll
        for (int kb = 0; kb < 4; ++kb)
          #pragma unroll
          for (int qb = 0; qb < 2; ++qb) {
            u16x4 w;
            #pragma unroll
            for (int rr = 0; rr < 4; ++rr) w[rr] = f2bf(st[kb][qb][rr]);
            const int q = qb * 16 + r;
            *(u16x4*)&Ps[q * 64 + (((2 * kb + (g >> 1)) ^ (r & 7)) << 3) + (g & 1) * 4] = w;
          }
        // O^T += V^T * P^T
        #pragma unroll
        for (int kk = 0; kk < 2; ++kk) {
          bf16x8 pb[2];
          #pragma unroll
          for (int qb = 0; qb < 2; ++qb)
            pb[qb] = ld_frag(&Ps[(qb * 16 + r) * 64 + ((kk * 4 + g) ^ (r & 7)) * 8]);
          __builtin_amdgcn_s_setprio(1);
          #pragma unroll
          for (int db = 0; db < 6; ++db) {
            const bf16x8 va = ld_frag(&Vs[(db * 16 + r) * 64 + ((kk * 4 + g) ^ (r & 7)) * 8]);
            #pragma unroll
            for (int qb = 0; qb < 2; ++qb)
              o[db][qb] = __builtin_amdgcn_mfma_f32_16x16x32_bf16(va, pb[qb], o[db][qb], 0, 0, 0);
          }
          __builtin_amdgcn_s_setprio(0);
        }
      }
      __syncthreads();
    }

    // epilogue: normalize, transpose through LDS (per-wave region), coalesced stores
    const float inv_l[2] = {1.f / l_[0], 1.f / l_[1]};
    unsigned short* obuf = SMEM + wave * 3328;  // 32 x 104 per wave
    #pragma unroll
    for (int db = 0; db < 6; ++db)
      #pragma unroll
      for (int qb = 0; qb < 2; ++qb) {
        u16x4 w;
        #pragma unroll
        for (int rr = 0; rr < 4; ++rr) w[rr] = f2bf(o[db][qb][rr] * inv_l[qb]);
        *(u16x4*)&obuf[(qb * 16 + r) * 104 + db * 16 + g * 4] = w;
      }
    #pragma unroll
    for (int it = 0; it < 6; ++it) {
      const int cc = it * 64 + lane;
      const int qr = cc / 12, d0 = (cc % 12) * 8;
      *(u32x4*)&ctx[(size_t)(b * 2048 + q0 + qr) * 3072 + h * 96 + d0] =
          *(const u32x4*)&obuf[qr * 104 + d0];
    }
  }
}

extern "C" void kernel_launch(void* const* d_in, const int* in_sizes, int n_in,
                              void* d_out, int out_size, void* d_ws, size_t ws_size,
                              hipStream_t stream) {
  const float* hs   = (const float*)d_in[0];
  const float* cosp = (const float*)d_in[1];
  const float* sinp = (const float*)d_in[2];
  const float* wqkv = (const float*)d_in[4];
  const float* wo   = (const float*)d_in[5];
  float* out = (float*)d_out;

  // workspace layout (bf16 elems): qkv 18,874,368 | hsb 12,582,912 | wqb 14,155,776
  // after GEMM1: hsb region reused as vt (3,145,728) + wob (9,437,184); wqb as ctx.
  unsigned short* qkv = (unsigned short*)d_ws;
  unsigned short* hsb = qkv + 18874368;
  unsigned short* wqb = hsb + 12582912;
  unsigned short* vt  = hsb;
  unsigned short* wob = hsb + 3145728;
  unsigned short* ctx = wqb;

  cvt_bf16<<<12288, 256, 0, stream>>>(hs,   hsb, 3145728);
  cvt_bf16<<<13824, 256, 0, stream>>>(wqkv, wqb, 3538944);
  gemm8p<1><<<384, 512, 0, stream>>>(hsb, wqb, (void*)qkv, cosp, sinp, 4096, 4608, 3072);
  vtrans<<<dim3(32, 8, 2), 256, 0, stream>>>(qkv, vt);
  cvt_bf16<<<9216, 256, 0, stream>>>(wo, wob, 2359296);
  attn_fwd<<<256, 512, 0, stream>>>(qkv, vt, ctx);
  gemm8p<0><<<256, 512, 0, stream>>>(ctx, wob, (void*)out, cosp, sinp, 4096, 3072, 3072);
}